// Round 4
// baseline (160.347 us; speedup 1.0000x reference)
//
#include <hip/hip_runtime.h>
#include <math.h>

// loss = ALPHA * mean(level_w * (softplus(x) - x*t))
//      + BETA  * sum_{b,e} relu(sig(x[b,dst]) - sig(x[b,src])) / (B*N)
//
// R9: 2-deep register prefetch + lgkm-only barriers (T3/T4 discipline).
// R8 post-mortem: per CU per step the memory system needs ~12.5K cyc to
// deliver 128 KB, but the 1-step prefetch window was only the ~6K-cyc
// gather phase, AND __syncthreads() drains vmcnt(0) at every barrier --
// the pipeline was structurally impossible. Fixes:
//  - issue group k+2's loads at step k (in-flight ~1.5 steps > delivery)
//  - raw s_barrier + manual "s_waitcnt lgkmcnt(0)" (cross-wave LDS
//    visibility) so prefetch VMEM crosses barriers un-drained
//  - edge indices staged in LDS as u16 (64 KB): the hot loop has NO vmem
//    ops except prefetch, so vmcnt counts stay clean (vmcnt is ordered --
//    any index reload would force a wait that drains the prefetch too)
//  - sched_barrier(0) pins phase order; full unroll = single BB, no sink.

#define ALPHA_C 1.0f
#define BETA_C  0.5f

constexpr int B = 4096;
constexpr int N = 4096;
constexpr int E = 16384;
constexpr int THREADS = 1024;
constexpr int GRID = 256;             // 1 block per CU
constexpr int R = 4;                  // rows per group (h4 gather width)
constexpr int ROWS_PB = B / GRID;     // 16 rows per block
constexpr int GPB = ROWS_PB / R;      // 4 pipeline steps per block
constexpr int EPT4 = E / 4 / THREADS; // 4 int4-chunks (16 edges) / thread

typedef _Float16 h4 __attribute__((ext_vector_type(4)));
typedef unsigned short us4 __attribute__((ext_vector_type(4)));

__global__ __launch_bounds__(64) void init_out_kernel(float* out) {
    if (threadIdx.x == 0) out[0] = 0.0f;
}

__device__ __forceinline__ void fast_sig_sp(float x, float& p, float& sp) {
    // q = exp(-|x|) in (0,1]; both sigmoid and softplus from one exp
    float q = __expf(-fabsf(x));
    float d = 1.0f + q;
    float r = __builtin_amdgcn_rcpf(d);     // ~1 ulp approx reciprocal
    p  = (x >= 0.0f) ? r : q * r;           // sigmoid
    sp = fmaxf(x, 0.0f) + __logf(d);        // softplus = max(x,0)+log(1+q)
}

__global__ __launch_bounds__(THREADS, 4) void hier_loss_kernel(
    const float* __restrict__ outputs,
    const float* __restrict__ targets,
    const float* __restrict__ level_w,
    const int*   __restrict__ edge_src,
    const int*   __restrict__ edge_dst,
    float*       __restrict__ out)
{
    __shared__ h4 P[2][N];              // 64 KB double-buffered fp16 sigmoid
    __shared__ unsigned short IS[E];    // 32 KB u16 src indices
    __shared__ unsigned short ID[E];    // 32 KB u16 dst indices

    const int tid  = threadIdx.x;
    const int row0 = blockIdx.x * ROWS_PB;

    const float4* out4 = (const float4*)outputs;
    const float4* tgt4 = (const float4*)targets;
    const float4* lw4  = (const float4*)level_w;
    const int4*   es4  = (const int4*)edge_src;
    const int4*   ed4  = (const int4*)edge_dst;
    us4* IS4 = (us4*)IS;
    us4* ID4 = (us4*)ID;

    float s1 = 0.0f, s2 = 0.0f;

    // ---- prologue: issue in order {w, idx}, L0, L1 ----
    const float4 w = lw4[tid];
    int4 sei[EPT4], dei[EPT4];
#pragma unroll
    for (int j = 0; j < EPT4; ++j) {
        sei[j] = es4[tid + j * THREADS];
        dei[j] = ed4[tid + j * THREADS];
    }
    float4 xs[2][R], ts[2][R];
#pragma unroll
    for (int g = 0; g < 2; ++g)
#pragma unroll
    for (int r = 0; r < R; ++r) {
        const size_t idx = (size_t)(row0 + g * R + r) * (N / 4) + tid;
        xs[g][r] = out4[idx];
        ts[g][r] = tgt4[idx];
    }
    __builtin_amdgcn_sched_barrier(0);

    const float wv[4] = {w.x, w.y, w.z, w.w};

    // pack idx -> LDS; compiler's wait here is counted (L0/L1 stay in flight)
#pragma unroll
    for (int j = 0; j < EPT4; ++j) {
        us4 ps = {(unsigned short)sei[j].x, (unsigned short)sei[j].y,
                  (unsigned short)sei[j].z, (unsigned short)sei[j].w};
        us4 pd = {(unsigned short)dei[j].x, (unsigned short)dei[j].y,
                  (unsigned short)dei[j].z, (unsigned short)dei[j].w};
        IS4[tid + j * THREADS] = ps;
        ID4[tid + j * THREADS] = pd;
    }
    __builtin_amdgcn_sched_barrier(0);

    // transform: slot regs -> BCE partial + fp16 transposed sigmoid into Pb
    auto transform = [&](int slot, h4* Pb) {
        h4 tmp[4];                      // tmp[k][r] = p(row r, node 4*tid+k)
#pragma unroll
        for (int r = 0; r < R; ++r) {
            const float xv[4] = {xs[slot][r].x, xs[slot][r].y,
                                 xs[slot][r].z, xs[slot][r].w};
            const float tv[4] = {ts[slot][r].x, ts[slot][r].y,
                                 ts[slot][r].z, ts[slot][r].w};
#pragma unroll
            for (int k = 0; k < 4; ++k) {
                float p, sp;
                fast_sig_sp(xv[k], p, sp);
                s1 = fmaf(wv[k], sp - xv[k] * tv[k], s1);
                tmp[k][r] = (_Float16)p;
            }
        }
#pragma unroll
        for (int k = 0; k < 4; ++k) Pb[4 * tid + k] = tmp[k];
    };

    // transform g0 -> P[0]; compiler waits counted vmcnt (L1 in flight)
    transform(0, P[0]);
    asm volatile("s_waitcnt lgkmcnt(0)" ::: "memory");  // idx+P0 visible
    __builtin_amdgcn_s_barrier();                       // no vmcnt drain
    __builtin_amdgcn_sched_barrier(0);

    // ---- pipelined steps: loads(k+2) cross barriers in flight ----
#pragma unroll
    for (int kg = 0; kg < GPB; ++kg) {
        // (1) issue loads for group kg+2 into the slot freed by group kg
        if (kg + 2 < GPB) {
            const int slot = kg & 1;
#pragma unroll
            for (int r = 0; r < R; ++r) {
                const size_t idx =
                    (size_t)(row0 + (kg + 2) * R + r) * (N / 4) + tid;
                xs[slot][r] = out4[idx];
                ts[slot][r] = tgt4[idx];
            }
        }
        __builtin_amdgcn_sched_barrier(0);

        // (2) edge gathers on P[kg&1]; pure-LDS phase (lgkm only)
        {
            const h4* Pc = P[kg & 1];
            h4 acc0 = {0, 0, 0, 0};
            h4 acc1 = {0, 0, 0, 0};
            const h4 zero = {0, 0, 0, 0};
#pragma unroll
            for (int j = 0; j < EPT4; ++j) {
                const us4 s = IS4[tid + j * THREADS];
                const us4 d = ID4[tid + j * THREADS];
                h4 a0 = Pc[s[0]], c0 = Pc[d[0]];
                h4 a1 = Pc[s[1]], c1 = Pc[d[1]];
                h4 a2 = Pc[s[2]], c2 = Pc[d[2]];
                h4 a3 = Pc[s[3]], c3 = Pc[d[3]];
                acc0 += __builtin_elementwise_max(c0 - a0, zero);   // v_pk_*
                acc1 += __builtin_elementwise_max(c1 - a1, zero);
                acc0 += __builtin_elementwise_max(c2 - a2, zero);
                acc1 += __builtin_elementwise_max(c3 - a3, zero);
            }
#pragma unroll
            for (int l = 0; l < 4; ++l) s2 += (float)acc0[l] + (float)acc1[l];
        }
        __builtin_amdgcn_sched_barrier(0);

        // (3) transform group kg+1 (landed a full step ago) -> other buffer
        if (kg + 1 < GPB) transform((kg + 1) & 1, P[(kg + 1) & 1]);

        // lgkm-only barrier: prefetch VMEM crosses un-drained
        asm volatile("s_waitcnt lgkmcnt(0)" ::: "memory");
        __builtin_amdgcn_s_barrier();
        __builtin_amdgcn_sched_barrier(0);
    }

    // ---- block reduce: wave64 shuffle, cross-wave via reused LDS ----
#pragma unroll
    for (int off = 32; off > 0; off >>= 1) {
        s1 += __shfl_down(s1, off, 64);
        s2 += __shfl_down(s2, off, 64);
    }
    float* red = (float*)P;              // safe: loop ended with a barrier
    const int wave = tid >> 6;           // 16 waves
    const int lane = tid & 63;
    if (lane == 0) { red[wave] = s1; red[16 + wave] = s2; }
    __syncthreads();                     // full drain fine in epilogue
    if (tid == 0) {
        float a = 0.0f, c = 0.0f;
#pragma unroll
        for (int v = 0; v < 16; ++v) { a += red[v]; c += red[16 + v]; }
        const float inv = 1.0f / ((float)B * (float)N);
        atomicAdd(out, (ALPHA_C * a + BETA_C * c) * inv);
    }
}

extern "C" void kernel_launch(void* const* d_in, const int* in_sizes, int n_in,
                              void* d_out, int out_size, void* d_ws, size_t ws_size,
                              hipStream_t stream) {
    const float* outputs = (const float*)d_in[0];
    const float* targets = (const float*)d_in[1];
    const float* level_w = (const float*)d_in[2];
    const int*   edge_src = (const int*)d_in[3];
    const int*   edge_dst = (const int*)d_in[4];
    float* out = (float*)d_out;

    init_out_kernel<<<1, 64, 0, stream>>>(out);
    hier_loss_kernel<<<GRID, THREADS, 0, stream>>>(outputs, targets, level_w,
                                                   edge_src, edge_dst, out);
}